// Round 1
// baseline (43626.022 us; speedup 1.0000x reference)
//
#include <hip/hip_runtime.h>
#include <hip/hip_bf16.h>
#include <math.h>

// PRNN: y_t = h_t @ Wdec^T + b_dec ; h_t = (1-s)h_{t-1} + s*a*tanh(x_t@Wenc^T + b_enc + h_{t-1}@Wrec^T + b_rec)
// B=256 T=512 NI=512 NH=2048 NO=256. Sequential scan over T; per step one fused GEMM
// [h|x_t](256x2560) @ [Wrec|Wenc]^T with split-K x2 (deterministic fixed-order combine),
// plus decoder y_{t-1} (16x16 tile per WG, uses previous h -> no extra dependency).

#define B_   256
#define T_   512
#define NI_  512
#define NH_  2048
#define NO_  256

typedef __bf16 bf16_t;
typedef __bf16 bf16x8 __attribute__((ext_vector_type(8)));
typedef __bf16 bf16x4 __attribute__((ext_vector_type(4)));
typedef float  f32x4  __attribute__((ext_vector_type(4)));

#define MFMA16(a, b, c) __builtin_amdgcn_mfma_f32_16x16x32_bf16((a), (b), (c), 0, 0, 0)

__global__ __launch_bounds__(256) void k_cvt(const float* __restrict__ src,
                                             bf16_t* __restrict__ dst, int n) {
  int i = blockIdx.x * 256 + threadIdx.x;
  const int stride = gridDim.x * 256;
  for (; i < n; i += stride) dst[i] = (bf16_t)src[i];
}

__global__ __launch_bounds__(256) void k_copy(const float* __restrict__ s,
                                              float* __restrict__ d, int n) {
  int i = blockIdx.x * 256 + threadIdx.x;
  const int stride = gridDim.x * 256;
  for (; i < n; i += stride) d[i] = s[i];
}

// Decoder: each WG computes one 16x16 tile of y_{t-1} = h_prev @ Wdec^T + b_dec.
// K=2048 split across the 4 waves, operands straight from global (L2-hot), LDS reduce.
__device__ __forceinline__ void dec_phase(int wgid, int tid,
    const bf16_t* __restrict__ hb_prev, const bf16_t* __restrict__ Wdec,
    const float* __restrict__ b_dec, float* __restrict__ y_out, void* lds) {
  const int lane = tid & 63;
  const int wv = tid >> 6;
  const int fl = lane & 15;
  const int kg = lane >> 4;
  const int dr = (wgid >> 4) * 16;   // batch rows
  const int dc = (wgid & 15) * 16;   // output cols
  f32x4 dacc = {0.f, 0.f, 0.f, 0.f};
  const int kw = wv * 512;
  #pragma unroll 4
  for (int ks = 0; ks < 16; ++ks) {
    const int k = kw + ks * 32 + kg * 8;
    bf16x8 af = *reinterpret_cast<const bf16x8*>(hb_prev + (size_t)(dr + fl) * NH_ + k);
    bf16x8 bf = *reinterpret_cast<const bf16x8*>(Wdec + (size_t)(dc + fl) * NH_ + k);
    dacc = MFMA16(af, bf, dacc);
  }
  float* Ds = reinterpret_cast<float*>(lds);   // 4KB
  __syncthreads();
  #pragma unroll
  for (int j = 0; j < 4; ++j)
    Ds[wv * 256 + (kg * 4 + j) * 16 + fl] = dacc[j];
  __syncthreads();
  const int er = tid >> 4, ec = tid & 15;
  const float yv = Ds[er * 16 + ec] + Ds[256 + er * 16 + ec]
                 + Ds[512 + er * 16 + ec] + Ds[768 + er * 16 + ec]
                 + b_dec[dc + ec];
  y_out[(size_t)(dr + er) * NO_ + (dc + ec)] = yv;
}

__global__ __launch_bounds__(256) void k_step(
    const int t, const int mode,   // mode 0: rec(+dec), mode 1: dec only (final y)
    const float* __restrict__ x,
    const float* __restrict__ dt_p, const float* __restrict__ a_p,
    const bf16_t* __restrict__ Wrec, const bf16_t* __restrict__ Wenc,
    const bf16_t* __restrict__ Wdec,
    const float* __restrict__ b_rec, const float* __restrict__ b_enc,
    const float* __restrict__ b_dec,
    const float* __restrict__ hf_prev, float* __restrict__ hf_cur,
    const bf16_t* __restrict__ hb_prev, bf16_t* __restrict__ hb_cur,
    float* __restrict__ y_out,
    float* __restrict__ partial, int* __restrict__ counters)
{
  __shared__ alignas(16) bf16_t As[64 * 64];
  __shared__ alignas(16) bf16_t Bs[64 * 64];
  __shared__ int s_rank;
  bf16x8* As8 = reinterpret_cast<bf16x8*>(As);
  bf16x8* Bs8 = reinterpret_cast<bf16x8*>(Bs);

  const int tid  = threadIdx.x;
  const int lane = tid & 63;
  const int wv   = tid >> 6;
  const int fl   = lane & 15;
  const int kg   = lane >> 4;
  const int wgid = blockIdx.x;

  if (mode == 1) {
    dec_phase(wgid, tid, hb_prev, Wdec, b_dec, y_out, (void*)As);
    return;
  }

  // wgid = rt*64 + ct*2 + sl  (row-tiles stride 64 => same W chunk lands on same XCD)
  const int rt = wgid >> 6;          // 0..3
  const int ct = (wgid & 63) >> 1;   // 0..31
  const int sl = wgid & 1;           // K-slice 0..1
  const int tile_id = rt * 32 + ct;  // 0..127
  const int brow = rt * 64;
  const int bcol = ct * 64;
  const int kbase = sl * 1280;       // composite K: [0,2048)=h|Wrec, [2048,2560)=x|Wenc

  const int wr = (wv >> 1) * 32;
  const int wc = (wv & 1) * 32;

  f32x4 acc[2][2];
  #pragma unroll
  for (int i = 0; i < 2; ++i)
    #pragma unroll
    for (int j = 0; j < 2; ++j) acc[i][j] = f32x4{0.f, 0.f, 0.f, 0.f};

  // staging: thread -> (row, 2 granules of 8 bf16); XOR swizzle g^(row&7) => conflict-free
  const int sr = tid >> 2;
  const int sc = tid & 3;
  const int g0 = 2 * sc, g1 = 2 * sc + 1;
  const int p0 = sr * 8 + (g0 ^ (sr & 7));
  const int p1 = sr * 8 + (g1 ^ (sr & 7));

  bf16x8 ra0, ra1, rb0, rb1;
  float4 fx0, fx1, fx2, fx3;
  bool cur_is_x = false;

  auto issue_loads = [&](int kt) {
    const int k0 = kbase + kt * 64;
    const int ka = k0 + g0 * 8;
    cur_is_x = (k0 >= NH_);
    if (!cur_is_x) {
      const bf16x8* pa = reinterpret_cast<const bf16x8*>(hb_prev + (size_t)(brow + sr) * NH_ + ka);
      ra0 = pa[0]; ra1 = pa[1];
    } else {
      const float* px = x + ((size_t)(brow + sr) * T_ + t) * NI_ + (ka - NH_);
      fx0 = reinterpret_cast<const float4*>(px)[0];
      fx1 = reinterpret_cast<const float4*>(px)[1];
      fx2 = reinterpret_cast<const float4*>(px)[2];
      fx3 = reinterpret_cast<const float4*>(px)[3];
    }
    const bf16_t* wb;
    if (k0 < NH_) wb = Wrec + (size_t)(bcol + sr) * NH_ + ka;
    else          wb = Wenc + (size_t)(bcol + sr) * NI_ + (ka - NH_);
    const bf16x8* pb = reinterpret_cast<const bf16x8*>(wb);
    rb0 = pb[0]; rb1 = pb[1];
  };

  issue_loads(0);
  const int KT = 20;   // 20 * 64 = 1280 per slice
  for (int kt = 0; kt < KT; ++kt) {
    bf16x8 va0, va1;
    if (!cur_is_x) { va0 = ra0; va1 = ra1; }
    else {
      va0 = bf16x8{(bf16_t)fx0.x, (bf16_t)fx0.y, (bf16_t)fx0.z, (bf16_t)fx0.w,
                   (bf16_t)fx1.x, (bf16_t)fx1.y, (bf16_t)fx1.z, (bf16_t)fx1.w};
      va1 = bf16x8{(bf16_t)fx2.x, (bf16_t)fx2.y, (bf16_t)fx2.z, (bf16_t)fx2.w,
                   (bf16_t)fx3.x, (bf16_t)fx3.y, (bf16_t)fx3.z, (bf16_t)fx3.w};
    }
    As8[p0] = va0; As8[p1] = va1;
    Bs8[p0] = rb0; Bs8[p1] = rb1;
    __syncthreads();
    if (kt + 1 < KT) issue_loads(kt + 1);   // prefetch overlaps MFMA below
    #pragma unroll
    for (int kh = 0; kh < 2; ++kh) {
      const int gb = kh * 4 + kg;
      const int sg = gb ^ (fl & 7);
      bf16x8 a0 = As8[(wr + fl) * 8 + sg];
      bf16x8 a1 = As8[(wr + 16 + fl) * 8 + sg];
      bf16x8 b0 = Bs8[(wc + fl) * 8 + sg];
      bf16x8 b1 = Bs8[(wc + 16 + fl) * 8 + sg];
      acc[0][0] = MFMA16(a0, b0, acc[0][0]);
      acc[0][1] = MFMA16(a0, b1, acc[0][1]);
      acc[1][0] = MFMA16(a1, b0, acc[1][0]);
      acc[1][1] = MFMA16(a1, b1, acc[1][1]);
    }
    __syncthreads();
  }

  // store split-K partial (deterministic: combiner sums slice0+slice1 in fixed order)
  float* ps = partial + ((size_t)tile_id * 2 + sl) * 4096;
  {
    const int orow = kg * 4;
    #pragma unroll
    for (int fm = 0; fm < 2; ++fm)
      #pragma unroll
      for (int fn = 0; fn < 2; ++fn)
        #pragma unroll
        for (int j = 0; j < 4; ++j) {
          const int rr = wr + fm * 16 + orow + j;
          const int cc = wc + fn * 16 + fl;
          ps[rr * 64 + cc] = acc[fm][fn][j];
        }
  }
  __threadfence();
  __syncthreads();
  if (tid == 0)
    s_rank = __hip_atomic_fetch_add(&counters[tile_id], 1, __ATOMIC_ACQ_REL,
                                    __HIP_MEMORY_SCOPE_AGENT);
  __syncthreads();
  const int rank = s_rank;

  // decoder for y_{t-1} (uses hb_prev only) — every WG does one 16x16 tile
  if (y_out != nullptr)
    dec_phase(wgid, tid, hb_prev, Wdec, b_dec, y_out, (void*)As);

  if (rank == 1) {   // second (last) slice to finish combines + gate epilogue
    __threadfence();
    const float* pA = partial + (size_t)tile_id * 2 * 4096;
    const float* pB = pA + 4096;
    const float sgate = 1.f / (1.f + expf(-dt_p[0]));
    const float av = a_p[0];
    const int rr = tid >> 2;
    const int c0 = (tid & 3) * 16;
    const int gr = brow + rr;
    #pragma unroll
    for (int q = 0; q < 4; ++q) {
      const int cc = c0 + q * 4;
      const int gc = bcol + cc;
      float4 u  = *reinterpret_cast<const float4*>(pA + rr * 64 + cc);
      float4 v  = *reinterpret_cast<const float4*>(pB + rr * 64 + cc);
      float4 br = *reinterpret_cast<const float4*>(b_rec + gc);
      float4 be = *reinterpret_cast<const float4*>(b_enc + gc);
      float4 hp = *reinterpret_cast<const float4*>(hf_prev + (size_t)gr * NH_ + gc);
      float4 o;
      o.x = (1.f - sgate) * hp.x + sgate * av * tanhf(u.x + v.x + br.x + be.x);
      o.y = (1.f - sgate) * hp.y + sgate * av * tanhf(u.y + v.y + br.y + be.y);
      o.z = (1.f - sgate) * hp.z + sgate * av * tanhf(u.z + v.z + br.z + be.z);
      o.w = (1.f - sgate) * hp.w + sgate * av * tanhf(u.w + v.w + br.w + be.w);
      *reinterpret_cast<float4*>(hf_cur + (size_t)gr * NH_ + gc) = o;
      bf16x4 ob = {(bf16_t)o.x, (bf16_t)o.y, (bf16_t)o.z, (bf16_t)o.w};
      *reinterpret_cast<bf16x4*>(hb_cur + (size_t)gr * NH_ + gc) = ob;
    }
    if (tid == 0)
      __hip_atomic_store(&counters[tile_id], 0, __ATOMIC_RELEASE,
                         __HIP_MEMORY_SCOPE_AGENT);
  }
}

extern "C" void kernel_launch(void* const* d_in, const int* in_sizes, int n_in,
                              void* d_out, int out_size, void* d_ws, size_t ws_size,
                              hipStream_t stream) {
  const float* x     = (const float*)d_in[0];
  const float* dt_p  = (const float*)d_in[1];
  const float* a_p   = (const float*)d_in[2];
  const float* W_enc = (const float*)d_in[3];
  const float* b_enc = (const float*)d_in[4];
  const float* W_rec = (const float*)d_in[5];
  const float* b_rec = (const float*)d_in[6];
  const float* W_dec = (const float*)d_in[7];
  const float* b_dec = (const float*)d_in[8];
  float* out = (float*)d_out;

  char* p = (char*)d_ws;
  float*  hf      = (float*)p;   p += 2 * (size_t)B_ * NH_ * 4;   // 4MB  f32 h master (2 slots)
  bf16_t* hb      = (bf16_t*)p;  p += 2 * (size_t)B_ * NH_ * 2;   // 2MB  bf16 h shadow
  bf16_t* Wrec_b  = (bf16_t*)p;  p += (size_t)NH_ * NH_ * 2;      // 8MB
  bf16_t* Wenc_b  = (bf16_t*)p;  p += (size_t)NH_ * NI_ * 2;      // 2MB
  bf16_t* Wdec_b  = (bf16_t*)p;  p += (size_t)NO_ * NH_ * 2;      // 1MB
  float*  partial = (float*)p;   p += (size_t)128 * 2 * 4096 * 4; // 4MB
  int*    counters= (int*)p;     p += 1024;

  hipMemsetAsync(hf, 0, (size_t)B_ * NH_ * 4, stream);
  hipMemsetAsync(hb, 0, (size_t)B_ * NH_ * 2, stream);
  hipMemsetAsync(counters, 0, 1024, stream);

  k_cvt<<<512, 256, 0, stream>>>(W_rec, Wrec_b, NH_ * NH_);
  k_cvt<<<128, 256, 0, stream>>>(W_enc, Wenc_b, NH_ * NI_);
  k_cvt<<<64, 256, 0, stream>>>(W_dec, Wdec_b, NO_ * NH_);

  float* y = out;
  float* hout = out + (size_t)T_ * B_ * NO_;

  for (int t = 0; t < T_; ++t) {
    const int ps = t & 1, cs = (t + 1) & 1;
    k_step<<<256, 256, 0, stream>>>(
        t, 0, x, dt_p, a_p, Wrec_b, Wenc_b, Wdec_b, b_rec, b_enc, b_dec,
        hf + (size_t)ps * B_ * NH_, hf + (size_t)cs * B_ * NH_,
        hb + (size_t)ps * B_ * NH_, hb + (size_t)cs * B_ * NH_,
        (t == 0) ? nullptr : (y + (size_t)(t - 1) * B_ * NO_),
        partial, counters);
  }
  // final y_{T-1} from h slot 0 (T even), then h output copy
  k_step<<<256, 256, 0, stream>>>(
      T_, 1, x, dt_p, a_p, Wrec_b, Wenc_b, Wdec_b, b_rec, b_enc, b_dec,
      hf, hf, hb, hb, y + (size_t)(T_ - 1) * B_ * NO_, partial, counters);
  k_copy<<<512, 256, 0, stream>>>(hf, hout, B_ * NH_);
}

// Round 3
// 22743.947 us; speedup vs baseline: 1.9181x; 1.9181x over previous
//
#include <hip/hip_runtime.h>
#include <hip/hip_bf16.h>
#include <math.h>

// PRNN persistent-kernel implementation (plain launch, static LDS, 23MB ws).
// y_t = h_t @ Wdec^T + b_dec ; h_t = (1-s)h_{t-1} + s*a*tanh(x_t@Wenc^T + b_enc + h_{t-1}@Wrec^T + b_rec)
// B=256 T=512 NI=512 NH=2048 NO=256.
// ONE kernel instance (256 WGs, 1/CU via 104KB static LDS) runs all 512 steps.
// 32 col-groups x 8 K-slices; each WG holds its 64-col x 320-K slice of [Wrec|Wenc]
// (composite K=2560) in LDS permanently. Per step: stage A (h bf16 / x f32->bf16)
// through a double-buffered LDS tile, accumulate 256x64 f32 partial, store to a
// single-buffered partial (reuse guarded by flag[cb] wait), group of 8 combines
// (8 cols each, fixed order => deterministic) + gate epilogue. Decoder y_{t-1}
// folded in per WG (16x16 tile). Sync: monotonic flags/ctrs, leader spin+acquire
// + barrier; release fetch_add after stores (buffer_wbl2 covers WG stores).

#define B_   256
#define T_   512
#define NI_  512
#define NH_  2048
#define NO_  256

#define NCB  32          // col groups (64 cols each)
#define NKB  8           // K slices (320 each, composite K = 2560)
#define KW   320
#define NCHUNK 5         // 5 x 64-K chunks per slice

typedef __bf16 bf16_t;
typedef __bf16 bf16x8 __attribute__((ext_vector_type(8)));
typedef float  f32x4  __attribute__((ext_vector_type(4)));

#define MFMA16(a,b,c) __builtin_amdgcn_mfma_f32_16x16x32_bf16((a),(b),(c),0,0,0)

__global__ __launch_bounds__(256) void k_cvt(const float* __restrict__ src,
                                             bf16_t* __restrict__ dst, int n) {
  int i = blockIdx.x * 256 + threadIdx.x;
  const int stride = gridDim.x * 256;
  for (; i < n; i += stride) dst[i] = (bf16_t)src[i];
}

__device__ __forceinline__ void spin_ge(int* p, int target) {
  while (__hip_atomic_load(p, __ATOMIC_RELAXED, __HIP_MEMORY_SCOPE_AGENT) < target)
    __builtin_amdgcn_s_sleep(2);
  (void)__hip_atomic_load(p, __ATOMIC_ACQUIRE, __HIP_MEMORY_SCOPE_AGENT);
}

// One 16x16 tile of y = h @ Wdec^T + b_dec per WG (K=2048 split over 4 waves).
__device__ __forceinline__ void dec_tile(int wgid, int tid,
    const bf16_t* __restrict__ hbp, const bf16_t* __restrict__ Wdec,
    const float* __restrict__ b_dec, float* __restrict__ y_out, float* Ds) {
  const int lane = tid & 63;
  const int wv2 = tid >> 6;
  const int fl = lane & 15;
  const int kg = lane >> 4;
  const int dr = (wgid >> 4) * 16;
  const int dc = (wgid & 15) * 16;
  f32x4 dacc = {0.f, 0.f, 0.f, 0.f};
  const int kw = wv2 * 512;
  #pragma unroll 4
  for (int ks = 0; ks < 16; ++ks) {
    const int k = kw + ks * 32 + kg * 8;
    bf16x8 af = *reinterpret_cast<const bf16x8*>(hbp + (size_t)(dr + fl) * NH_ + k);
    bf16x8 bf = *reinterpret_cast<const bf16x8*>(Wdec + (size_t)(dc + fl) * NH_ + k);
    dacc = MFMA16(af, bf, dacc);
  }
  __syncthreads();
  #pragma unroll
  for (int j = 0; j < 4; ++j)
    Ds[wv2 * 256 + (kg * 4 + j) * 16 + fl] = dacc[j];
  __syncthreads();
  const int er = tid >> 4, ec = tid & 15;
  y_out[(size_t)(dr + er) * NO_ + (dc + ec)] =
      Ds[er * 16 + ec] + Ds[256 + er * 16 + ec] + Ds[512 + er * 16 + ec] +
      Ds[768 + er * 16 + ec] + b_dec[dc + ec];
}

__global__ __launch_bounds__(256, 1) void k_prnn(
    const float* __restrict__ x,
    const float* __restrict__ dt_p, const float* __restrict__ a_p,
    const float* __restrict__ Wrec, const float* __restrict__ Wenc,
    const bf16_t* __restrict__ Wdec,
    const float* __restrict__ b_rec, const float* __restrict__ b_enc,
    const float* __restrict__ b_dec,
    float* __restrict__ hf, bf16_t* __restrict__ hb,
    float* __restrict__ partial, int* __restrict__ sync_,
    float* __restrict__ out)
{
  __shared__ alignas(16) bf16x8 Wl[64 * 40];      // 40KB  W slice, LDS-resident
  __shared__ alignas(16) bf16x8 Abuf[2 * 2048];   // 64KB  A double-buffer
  float* Ds = reinterpret_cast<float*>(Abuf);     // 4KB decoder scratch (Abuf dead then)

  const int tid  = threadIdx.x;
  const int lane = tid & 63;
  const int wv   = tid >> 6;
  const int fl   = lane & 15;
  const int kg   = lane >> 4;
  const int bid  = blockIdx.x;
  const int cb   = bid & 31;   // col group
  const int kb   = bid >> 5;   // K slice
  int* flags = sync_;          // flag[cb] at [cb*16]  (64B strided)
  int* ctrs  = sync_ + 512;    // counter[cb] at [512 + cb*16]

  const float sgate = 1.f / (1.f + expf(-dt_p[0]));
  const float av = a_p[0];
  const float gi = 1.f - sgate;

  // ---- prologue: load W slice (cols cb*64..+64, composite k kb*320..+320) into LDS
  {
    const int c = tid >> 2;             // 0..63 (local col)
    const int c_g = cb * 64 + c;
    const int sub = tid & 3;
    #pragma unroll
    for (int i = 0; i < 10; ++i) {
      const int gW = sub + 4 * i;       // 0..39
      const int k = kb * KW + gW * 8;
      const float* src = (k < NH_) ? (Wrec + (size_t)c_g * NH_ + k)
                                   : (Wenc + (size_t)c_g * NI_ + (k - NH_));
      float4 f0 = reinterpret_cast<const float4*>(src)[0];
      float4 f1 = reinterpret_cast<const float4*>(src)[1];
      bf16x8 w8 = {(bf16_t)f0.x, (bf16_t)f0.y, (bf16_t)f0.z, (bf16_t)f0.w,
                   (bf16_t)f1.x, (bf16_t)f1.y, (bf16_t)f1.z, (bf16_t)f1.w};
      Wl[c * 40 + (gW ^ (c & 7))] = w8;
    }
  }
  __syncthreads();

  // chunk-wait set for this slice (h chunks are 64-col groups)
  int wfirst = 0, wcount = 0;
  if (kb <= 5)      { wfirst = kb * 5; wcount = 5; }
  else if (kb == 6) { wfirst = 30;     wcount = 2; }

  for (int t = 0; t < T_; ++t) {
    const int par_in = t & 1;
    const float*  hf_in  = hf + (size_t)par_in * B_ * NH_;
    float*        hf_out = hf + (size_t)(par_in ^ 1) * B_ * NH_;
    const bf16_t* hb_in  = hb + (size_t)par_in * B_ * NH_;
    bf16_t*       hb_out = hb + (size_t)(par_in ^ 1) * B_ * NH_;

    // ---- wait: h chunks this slice reads (level 8t = combines of t-1 done),
    //            plus flag[cb] (partial single-buffer reuse guard)
    if (tid < wcount)   spin_ge(flags + (wfirst + tid) * 16, 8 * t);
    if (tid == wcount)  spin_ge(flags + cb * 16, 8 * t);
    __syncthreads();

    // ---- GEMM: acc[256 x 64] over K=320 in 5 double-buffered 64-K chunks
    f32x4 acc[4][4];
    #pragma unroll
    for (int i = 0; i < 4; ++i)
      #pragma unroll
      for (int j = 0; j < 4; ++j) acc[i][j] = f32x4{0.f, 0.f, 0.f, 0.f};

    bf16x8 sh[8];
    float4 sx[16];
    bool cx = false;
    auto load_chunk = [&](int c) {
      const int k0 = kb * KW + c * 64;
      cx = (k0 >= NH_);
      if (!cx) {
        const bf16x8* src = reinterpret_cast<const bf16x8*>(hb_in + (size_t)tid * NH_ + k0);
        #pragma unroll
        for (int g = 0; g < 8; ++g) sh[g] = src[g];
      } else {
        const float4* src = reinterpret_cast<const float4*>(
            x + ((size_t)tid * T_ + t) * NI_ + (k0 - NH_));
        #pragma unroll
        for (int q = 0; q < 16; ++q) sx[q] = src[q];
      }
    };

    load_chunk(0);
    #pragma unroll 1
    for (int c = 0; c < NCHUNK; ++c) {
      bf16x8* Ab = Abuf + (c & 1) * 2048;
      __syncthreads();
      if (!cx) {
        #pragma unroll
        for (int g = 0; g < 8; ++g) Ab[tid * 8 + (g ^ (tid & 7))] = sh[g];
      } else {
        #pragma unroll
        for (int g = 0; g < 8; ++g) {
          float4 u = sx[2 * g], v2 = sx[2 * g + 1];
          bf16x8 w8 = {(bf16_t)u.x, (bf16_t)u.y, (bf16_t)u.z, (bf16_t)u.w,
                       (bf16_t)v2.x, (bf16_t)v2.y, (bf16_t)v2.z, (bf16_t)v2.w};
          Ab[tid * 8 + (g ^ (tid & 7))] = w8;
        }
      }
      __syncthreads();
      if (c + 1 < NCHUNK) load_chunk(c + 1);   // prefetch overlaps MFMA below
      #pragma unroll
      for (int ks = 0; ks < 2; ++ks) {
        const int sA = (ks * 4 + kg) ^ (fl & 7);
        const int sW = (c * 8 + ks * 4 + kg) ^ (fl & 7);
        bf16x8 a0 = Ab[(wv * 64 +  0 + fl) * 8 + sA];
        bf16x8 a1 = Ab[(wv * 64 + 16 + fl) * 8 + sA];
        bf16x8 a2 = Ab[(wv * 64 + 32 + fl) * 8 + sA];
        bf16x8 a3 = Ab[(wv * 64 + 48 + fl) * 8 + sA];
        bf16x8 b0 = Wl[( 0 + fl) * 40 + sW];
        bf16x8 b1 = Wl[(16 + fl) * 40 + sW];
        bf16x8 b2 = Wl[(32 + fl) * 40 + sW];
        bf16x8 b3 = Wl[(48 + fl) * 40 + sW];
        acc[0][0] = MFMA16(a0, b0, acc[0][0]);
        acc[0][1] = MFMA16(a0, b1, acc[0][1]);
        acc[0][2] = MFMA16(a0, b2, acc[0][2]);
        acc[0][3] = MFMA16(a0, b3, acc[0][3]);
        acc[1][0] = MFMA16(a1, b0, acc[1][0]);
        acc[1][1] = MFMA16(a1, b1, acc[1][1]);
        acc[1][2] = MFMA16(a1, b2, acc[1][2]);
        acc[1][3] = MFMA16(a1, b3, acc[1][3]);
        acc[2][0] = MFMA16(a2, b0, acc[2][0]);
        acc[2][1] = MFMA16(a2, b1, acc[2][1]);
        acc[2][2] = MFMA16(a2, b2, acc[2][2]);
        acc[2][3] = MFMA16(a2, b3, acc[2][3]);
        acc[3][0] = MFMA16(a3, b0, acc[3][0]);
        acc[3][1] = MFMA16(a3, b1, acc[3][1]);
        acc[3][2] = MFMA16(a3, b2, acc[3][2]);
        acc[3][3] = MFMA16(a3, b3, acc[3][3]);
      }
    }

    // ---- store f32 partial (single-buffered; reuse guarded by flag[cb] wait above)
    {
      float* ps = partial + ((size_t)cb * NKB + kb) * 16384;
      #pragma unroll
      for (int i = 0; i < 4; ++i)
        #pragma unroll
        for (int j = 0; j < 4; ++j)
          #pragma unroll
          for (int jj = 0; jj < 4; ++jj)
            ps[(wv * 64 + i * 16 + kg * 4 + jj) * 64 + (j * 16 + fl)] = acc[i][j][jj];
    }
    __syncthreads();   // each wave drains its stores (vmcnt 0) before the release below
    if (tid == 0)
      __hip_atomic_fetch_add(ctrs + cb * 16, 1, __ATOMIC_RELEASE, __HIP_MEMORY_SCOPE_AGENT);

    // ---- decoder for y_{t-1} (reads full hb_in; overlaps other groups' tails)
    if (t >= 1) {
      if (tid < 32) spin_ge(flags + tid * 16, 8 * t);
      __syncthreads();
      dec_tile(bid, tid, hb_in, Wdec, b_dec, out + (size_t)(t - 1) * B_ * NO_, Ds);
    }

    // ---- combine: this WG handles cols [cb*64 + kb*8, +8) for all 256 rows
    if (tid == 0) spin_ge(ctrs + cb * 16, 8 * (t + 1));
    __syncthreads();
    {
      const float* pb = partial + (size_t)cb * NKB * 16384;
      const int r = tid;
      const int jc = kb * 8;
      float v0 = 0.f, v1 = 0.f, v2 = 0.f, v3 = 0.f, v4 = 0.f, v5 = 0.f, v6 = 0.f, v7 = 0.f;
      #pragma unroll
      for (int kk = 0; kk < NKB; ++kk) {
        const float4* row = reinterpret_cast<const float4*>(pb + (size_t)kk * 16384 + r * 64 + jc);
        float4 u = row[0], w = row[1];
        v0 += u.x; v1 += u.y; v2 += u.z; v3 += u.w;
        v4 += w.x; v5 += w.y; v6 += w.z; v7 += w.w;
      }
      const int cg = cb * 64 + jc;
      float4 br0 = *reinterpret_cast<const float4*>(b_rec + cg);
      float4 br1 = *reinterpret_cast<const float4*>(b_rec + cg + 4);
      float4 be0 = *reinterpret_cast<const float4*>(b_enc + cg);
      float4 be1 = *reinterpret_cast<const float4*>(b_enc + cg + 4);
      const float* hpr = hf_in + (size_t)r * NH_ + cg;
      float4 h0 = reinterpret_cast<const float4*>(hpr)[0];
      float4 h1 = reinterpret_cast<const float4*>(hpr)[1];
      float4 o0, o1;
      o0.x = gi * h0.x + sgate * av * tanhf(v0 + br0.x + be0.x);
      o0.y = gi * h0.y + sgate * av * tanhf(v1 + br0.y + be0.y);
      o0.z = gi * h0.z + sgate * av * tanhf(v2 + br0.z + be0.z);
      o0.w = gi * h0.w + sgate * av * tanhf(v3 + br0.w + be0.w);
      o1.x = gi * h1.x + sgate * av * tanhf(v4 + br1.x + be1.x);
      o1.y = gi * h1.y + sgate * av * tanhf(v5 + br1.y + be1.y);
      o1.z = gi * h1.z + sgate * av * tanhf(v6 + br1.z + be1.z);
      o1.w = gi * h1.w + sgate * av * tanhf(v7 + br1.w + be1.w);
      float* hor = hf_out + (size_t)r * NH_ + cg;
      reinterpret_cast<float4*>(hor)[0] = o0;
      reinterpret_cast<float4*>(hor)[1] = o1;
      bf16x8 ob = {(bf16_t)o0.x, (bf16_t)o0.y, (bf16_t)o0.z, (bf16_t)o0.w,
                   (bf16_t)o1.x, (bf16_t)o1.y, (bf16_t)o1.z, (bf16_t)o1.w};
      *reinterpret_cast<bf16x8*>(hb_out + (size_t)r * NH_ + cg) = ob;
    }
    __syncthreads();   // drain h stores
    if (tid == 0)
      __hip_atomic_fetch_add(flags + cb * 16, 1, __ATOMIC_RELEASE, __HIP_MEMORY_SCOPE_AGENT);
  }

  // ---- epilogue: y_{T-1} (h_{511} lives at parity 0) + h_final copy
  if (tid < 32) spin_ge(flags + tid * 16, 8 * T_);
  __syncthreads();
  dec_tile(bid, tid, hb /*par0*/, Wdec, b_dec, out + (size_t)(T_ - 1) * B_ * NO_, Ds);
  {
    float* hdst = out + (size_t)T_ * B_ * NO_;
    const int idx = bid * 2048 + tid * 8;
    float4 u = reinterpret_cast<const float4*>(hf + idx)[0];
    float4 w = reinterpret_cast<const float4*>(hf + idx)[1];
    reinterpret_cast<float4*>(hdst + idx)[0] = u;
    reinterpret_cast<float4*>(hdst + idx)[1] = w;
  }
}

extern "C" void kernel_launch(void* const* d_in, const int* in_sizes, int n_in,
                              void* d_out, int out_size, void* d_ws, size_t ws_size,
                              hipStream_t stream) {
  const float* x     = (const float*)d_in[0];
  const float* dt_p  = (const float*)d_in[1];
  const float* a_p   = (const float*)d_in[2];
  const float* W_enc = (const float*)d_in[3];
  const float* b_enc = (const float*)d_in[4];
  const float* W_rec = (const float*)d_in[5];
  const float* b_rec = (const float*)d_in[6];
  const float* W_dec = (const float*)d_in[7];
  const float* b_dec = (const float*)d_in[8];
  float* out = (float*)d_out;

  char* p = (char*)d_ws;
  float*  hf      = (float*)p;   p += 2 * (size_t)B_ * NH_ * 4;        // 4MB
  bf16_t* hb      = (bf16_t*)p;  p += 2 * (size_t)B_ * NH_ * 2;        // 2MB
  bf16_t* Wdec_b  = (bf16_t*)p;  p += (size_t)NO_ * NH_ * 2;           // 1MB
  float*  partial = (float*)p;   p += (size_t)NCB * NKB * 16384 * 4;   // 16MB
  int*    sync_   = (int*)p;     p += 4096;                            // ~23MB total

  hipMemsetAsync(hf, 0, (size_t)B_ * NH_ * 4, stream);   // parity-0 h = 0
  hipMemsetAsync(hb, 0, (size_t)B_ * NH_ * 2, stream);
  hipMemsetAsync(sync_, 0, 4096, stream);

  k_cvt<<<64, 256, 0, stream>>>(W_dec, Wdec_b, NO_ * NH_);

  k_prnn<<<dim3(256), dim3(256), 0, stream>>>(
      x, dt_p, a_p, W_rec, W_enc, Wdec_b, b_rec, b_enc, b_dec,
      hf, hb, partial, sync_, out);
}

// Round 5
// 22559.357 us; speedup vs baseline: 1.9338x; 1.0082x over previous
//
#include <hip/hip_runtime.h>
#include <hip/hip_bf16.h>
#include <math.h>

// PRNN persistent-kernel, round 5: round-3 skeleton + non-temporal rendezvous data
// (partials/hb/y bypass L2 so agent-scope release wbl2-drain is ~free) + f32 master
// h state held in registers for the whole 512-step loop (never touches memory).
// y_t = h_t @ Wdec^T + b_dec ; h_t = (1-s)h_{t-1} + s*a*tanh(x_t@Wenc^T + b_enc + h_{t-1}@Wrec^T + b_rec)
// B=256 T=512 NI=512 NH=2048 NO=256.
// 256 WGs = 32 col-groups x 8 K-slices; W slice (64 cols x 320 composite-K) LDS-resident.

#define B_   256
#define T_   512
#define NI_  512
#define NH_  2048
#define NO_  256

#define NCB  32          // col groups (64 cols each)
#define NKB  8           // K slices (320 each, composite K = 2560)
#define KW   320
#define NCHUNK 5         // 5 x 64-K chunks per slice

typedef __bf16 bf16_t;
typedef __bf16 bf16x8 __attribute__((ext_vector_type(8)));
typedef float  f32x4  __attribute__((ext_vector_type(4)));

#define MFMA16(a,b,c) __builtin_amdgcn_mfma_f32_16x16x32_bf16((a),(b),(c),0,0,0)

__device__ __forceinline__ void nt_store_f(float v, float* p) {
  __builtin_nontemporal_store(v, p);
}
__device__ __forceinline__ void nt_store_v4(f32x4 v, float* p) {
  __builtin_nontemporal_store(v, reinterpret_cast<f32x4*>(p));
}

__global__ __launch_bounds__(256) void k_cvt(const float* __restrict__ src,
                                             bf16_t* __restrict__ dst, int n) {
  int i = blockIdx.x * 256 + threadIdx.x;
  const int stride = gridDim.x * 256;
  for (; i < n; i += stride) dst[i] = (bf16_t)src[i];
}

__device__ __forceinline__ void spin_ge(int* p, int target) {
  while (__hip_atomic_load(p, __ATOMIC_RELAXED, __HIP_MEMORY_SCOPE_AGENT) < target)
    __builtin_amdgcn_s_sleep(2);
  (void)__hip_atomic_load(p, __ATOMIC_ACQUIRE, __HIP_MEMORY_SCOPE_AGENT);
}

// One 16x16 tile of y = h @ Wdec^T + b_dec per WG (K=2048 split over 4 waves).
__device__ __forceinline__ void dec_tile(int wgid, int tid,
    const bf16_t* __restrict__ hbp, const bf16_t* __restrict__ Wdec,
    const float* __restrict__ b_dec, float* __restrict__ y_out, float* Ds) {
  const int lane = tid & 63;
  const int wv2 = tid >> 6;
  const int fl = lane & 15;
  const int kg = lane >> 4;
  const int dr = (wgid >> 4) * 16;
  const int dc = (wgid & 15) * 16;
  f32x4 dacc = {0.f, 0.f, 0.f, 0.f};
  const int kw = wv2 * 512;
  #pragma unroll 4
  for (int ks = 0; ks < 16; ++ks) {
    const int k = kw + ks * 32 + kg * 8;
    bf16x8 af = *reinterpret_cast<const bf16x8*>(hbp + (size_t)(dr + fl) * NH_ + k);
    bf16x8 bf = *reinterpret_cast<const bf16x8*>(Wdec + (size_t)(dc + fl) * NH_ + k);
    dacc = MFMA16(af, bf, dacc);
  }
  __syncthreads();
  #pragma unroll
  for (int j = 0; j < 4; ++j)
    Ds[wv2 * 256 + (kg * 4 + j) * 16 + fl] = dacc[j];
  __syncthreads();
  const int er = tid >> 4, ec = tid & 15;
  const float yv = Ds[er * 16 + ec] + Ds[256 + er * 16 + ec] + Ds[512 + er * 16 + ec] +
                   Ds[768 + er * 16 + ec] + b_dec[dc + ec];
  nt_store_f(yv, &y_out[(size_t)(dr + er) * NO_ + (dc + ec)]);
}

__global__ __launch_bounds__(256, 1) void k_prnn(
    const float* __restrict__ x,
    const float* __restrict__ dt_p, const float* __restrict__ a_p,
    const float* __restrict__ Wrec, const float* __restrict__ Wenc,
    const bf16_t* __restrict__ Wdec,
    const float* __restrict__ b_rec, const float* __restrict__ b_enc,
    const float* __restrict__ b_dec,
    bf16_t* __restrict__ hb,
    float* __restrict__ partial, int* __restrict__ sync_,
    float* __restrict__ out)
{
  __shared__ alignas(16) bf16x8 Wl[64 * 40];      // 40KB  W slice, LDS-resident
  __shared__ alignas(16) bf16x8 Abuf[2 * 2048];   // 64KB  A double-buffer
  float* Ds = reinterpret_cast<float*>(Abuf);     // 4KB decoder scratch (Abuf dead then)

  const int tid  = threadIdx.x;
  const int lane = tid & 63;
  const int wv   = tid >> 6;
  const int fl   = lane & 15;
  const int kg   = lane >> 4;
  const int bid  = blockIdx.x;
  const int cb   = bid & 31;   // col group
  const int kb   = bid >> 5;   // K slice
  int* flags = sync_;          // flag[cb] at [cb*16]  (64B strided)
  int* ctrs  = sync_ + 512;    // counter[cb] at [512 + cb*16]

  const float sgate = 1.f / (1.f + expf(-dt_p[0]));
  const float av = a_p[0];
  const float gi = 1.f - sgate;

  // f32 master h state for this thread's 8 owned elements:
  // row = tid, cols = cb*64 + kb*8 + 0..8 — same ownership every step.
  float hr[8];
  #pragma unroll
  for (int i = 0; i < 8; ++i) hr[i] = 0.f;

  // ---- prologue: load W slice (cols cb*64..+64, composite k kb*320..+320) into LDS
  {
    const int c = tid >> 2;             // 0..63 (local col)
    const int c_g = cb * 64 + c;
    const int sub = tid & 3;
    #pragma unroll
    for (int i = 0; i < 10; ++i) {
      const int gW = sub + 4 * i;       // 0..39
      const int k = kb * KW + gW * 8;
      const float* src = (k < NH_) ? (Wrec + (size_t)c_g * NH_ + k)
                                   : (Wenc + (size_t)c_g * NI_ + (k - NH_));
      float4 f0 = reinterpret_cast<const float4*>(src)[0];
      float4 f1 = reinterpret_cast<const float4*>(src)[1];
      bf16x8 w8 = {(bf16_t)f0.x, (bf16_t)f0.y, (bf16_t)f0.z, (bf16_t)f0.w,
                   (bf16_t)f1.x, (bf16_t)f1.y, (bf16_t)f1.z, (bf16_t)f1.w};
      Wl[c * 40 + (gW ^ (c & 7))] = w8;
    }
  }
  __syncthreads();

  // chunk-wait set for this slice (h chunks are 64-col groups)
  int wfirst = 0, wcount = 0;
  if (kb <= 5)      { wfirst = kb * 5; wcount = 5; }
  else if (kb == 6) { wfirst = 30;     wcount = 2; }

  for (int t = 0; t < T_; ++t) {
    const int par_in = t & 1;
    const bf16_t* hb_in  = hb + (size_t)par_in * B_ * NH_;
    bf16_t*       hb_out = hb + (size_t)(par_in ^ 1) * B_ * NH_;

    // ---- wait: h chunks this slice reads (level 8t = combines of t-1 done),
    //            plus flag[cb] (partial single-buffer reuse guard)
    if (tid < wcount)   spin_ge(flags + (wfirst + tid) * 16, 8 * t);
    if (tid == wcount)  spin_ge(flags + cb * 16, 8 * t);
    __syncthreads();

    // ---- GEMM: acc[256 x 64] over K=320 in 5 double-buffered 64-K chunks
    f32x4 acc[4][4];
    #pragma unroll
    for (int i = 0; i < 4; ++i)
      #pragma unroll
      for (int j = 0; j < 4; ++j) acc[i][j] = f32x4{0.f, 0.f, 0.f, 0.f};

    bf16x8 sh[8];
    float4 sx[16];
    bool cx = false;
    auto load_chunk = [&](int c) {
      const int k0 = kb * KW + c * 64;
      cx = (k0 >= NH_);
      if (!cx) {
        const bf16x8* src = reinterpret_cast<const bf16x8*>(hb_in + (size_t)tid * NH_ + k0);
        #pragma unroll
        for (int g = 0; g < 8; ++g) sh[g] = src[g];
      } else {
        const float4* src = reinterpret_cast<const float4*>(
            x + ((size_t)tid * T_ + t) * NI_ + (k0 - NH_));
        #pragma unroll
        for (int q = 0; q < 16; ++q) sx[q] = src[q];
      }
    };

    load_chunk(0);
    #pragma unroll 1
    for (int c = 0; c < NCHUNK; ++c) {
      bf16x8* Ab = Abuf + (c & 1) * 2048;
      __syncthreads();
      if (!cx) {
        #pragma unroll
        for (int g = 0; g < 8; ++g) Ab[tid * 8 + (g ^ (tid & 7))] = sh[g];
      } else {
        #pragma unroll
        for (int g = 0; g < 8; ++g) {
          float4 u = sx[2 * g], v2 = sx[2 * g + 1];
          bf16x8 w8 = {(bf16_t)u.x, (bf16_t)u.y, (bf16_t)u.z, (bf16_t)u.w,
                       (bf16_t)v2.x, (bf16_t)v2.y, (bf16_t)v2.z, (bf16_t)v2.w};
          Ab[tid * 8 + (g ^ (tid & 7))] = w8;
        }
      }
      __syncthreads();
      if (c + 1 < NCHUNK) load_chunk(c + 1);   // prefetch overlaps MFMA below
      #pragma unroll
      for (int ks = 0; ks < 2; ++ks) {
        const int sA = (ks * 4 + kg) ^ (fl & 7);
        const int sW = (c * 8 + ks * 4 + kg) ^ (fl & 7);
        bf16x8 a0 = Ab[(wv * 64 +  0 + fl) * 8 + sA];
        bf16x8 a1 = Ab[(wv * 64 + 16 + fl) * 8 + sA];
        bf16x8 a2 = Ab[(wv * 64 + 32 + fl) * 8 + sA];
        bf16x8 a3 = Ab[(wv * 64 + 48 + fl) * 8 + sA];
        bf16x8 b0 = Wl[( 0 + fl) * 40 + sW];
        bf16x8 b1 = Wl[(16 + fl) * 40 + sW];
        bf16x8 b2 = Wl[(32 + fl) * 40 + sW];
        bf16x8 b3 = Wl[(48 + fl) * 40 + sW];
        acc[0][0] = MFMA16(a0, b0, acc[0][0]);
        acc[0][1] = MFMA16(a0, b1, acc[0][1]);
        acc[0][2] = MFMA16(a0, b2, acc[0][2]);
        acc[0][3] = MFMA16(a0, b3, acc[0][3]);
        acc[1][0] = MFMA16(a1, b0, acc[1][0]);
        acc[1][1] = MFMA16(a1, b1, acc[1][1]);
        acc[1][2] = MFMA16(a1, b2, acc[1][2]);
        acc[1][3] = MFMA16(a1, b3, acc[1][3]);
        acc[2][0] = MFMA16(a2, b0, acc[2][0]);
        acc[2][1] = MFMA16(a2, b1, acc[2][1]);
        acc[2][2] = MFMA16(a2, b2, acc[2][2]);
        acc[2][3] = MFMA16(a2, b3, acc[2][3]);
        acc[3][0] = MFMA16(a3, b0, acc[3][0]);
        acc[3][1] = MFMA16(a3, b1, acc[3][1]);
        acc[3][2] = MFMA16(a3, b2, acc[3][2]);
        acc[3][3] = MFMA16(a3, b3, acc[3][3]);
      }
    }

    // ---- store f32 partial NON-TEMPORAL (bypass L2 => releases have ~no dirty L2)
    {
      float* ps = partial + ((size_t)cb * NKB + kb) * 16384;
      #pragma unroll
      for (int i = 0; i < 4; ++i)
        #pragma unroll
        for (int j = 0; j < 4; ++j)
          #pragma unroll
          for (int jj = 0; jj < 4; ++jj)
            nt_store_f(acc[i][j][jj],
                       &ps[(wv * 64 + i * 16 + kg * 4 + jj) * 64 + (j * 16 + fl)]);
    }
    __syncthreads();   // each wave drains its stores (vmcnt 0) before the release below
    if (tid == 0)
      __hip_atomic_fetch_add(ctrs + cb * 16, 1, __ATOMIC_RELEASE, __HIP_MEMORY_SCOPE_AGENT);

    // ---- decoder for y_{t-1} (reads full hb_in; overlaps other groups' tails)
    if (t >= 1) {
      if (tid < 32) spin_ge(flags + tid * 16, 8 * t);
      __syncthreads();
      dec_tile(bid, tid, hb_in, Wdec, b_dec, out + (size_t)(t - 1) * B_ * NO_, Ds);
    }

    // ---- combine: this WG handles cols [cb*64 + kb*8, +8) for all 256 rows
    if (tid == 0) spin_ge(ctrs + cb * 16, 8 * (t + 1));
    __syncthreads();
    {
      const float* pb = partial + (size_t)cb * NKB * 16384;
      const int r = tid;
      const int jc = kb * 8;
      float v0 = 0.f, v1 = 0.f, v2 = 0.f, v3 = 0.f, v4 = 0.f, v5 = 0.f, v6 = 0.f, v7 = 0.f;
      #pragma unroll
      for (int kk = 0; kk < NKB; ++kk) {
        const float4* row = reinterpret_cast<const float4*>(pb + (size_t)kk * 16384 + r * 64 + jc);
        float4 u = row[0], w = row[1];
        v0 += u.x; v1 += u.y; v2 += u.z; v3 += u.w;
        v4 += w.x; v5 += w.y; v6 += w.z; v7 += w.w;
      }
      const int cg = cb * 64 + jc;
      float4 br0 = *reinterpret_cast<const float4*>(b_rec + cg);
      float4 br1 = *reinterpret_cast<const float4*>(b_rec + cg + 4);
      float4 be0 = *reinterpret_cast<const float4*>(b_enc + cg);
      float4 be1 = *reinterpret_cast<const float4*>(b_enc + cg + 4);
      f32x4 o0, o1;
      o0[0] = gi * hr[0] + sgate * av * tanhf(v0 + br0.x + be0.x);
      o0[1] = gi * hr[1] + sgate * av * tanhf(v1 + br0.y + be0.y);
      o0[2] = gi * hr[2] + sgate * av * tanhf(v2 + br0.z + be0.z);
      o0[3] = gi * hr[3] + sgate * av * tanhf(v3 + br0.w + be0.w);
      o1[0] = gi * hr[4] + sgate * av * tanhf(v4 + br1.x + be1.x);
      o1[1] = gi * hr[5] + sgate * av * tanhf(v5 + br1.y + be1.y);
      o1[2] = gi * hr[6] + sgate * av * tanhf(v6 + br1.z + be1.z);
      o1[3] = gi * hr[7] + sgate * av * tanhf(v7 + br1.w + be1.w);
      hr[0] = o0[0]; hr[1] = o0[1]; hr[2] = o0[2]; hr[3] = o0[3];
      hr[4] = o1[0]; hr[5] = o1[1]; hr[6] = o1[2]; hr[7] = o1[3];
      bf16x8 ob = {(bf16_t)o0[0], (bf16_t)o0[1], (bf16_t)o0[2], (bf16_t)o0[3],
                   (bf16_t)o1[0], (bf16_t)o1[1], (bf16_t)o1[2], (bf16_t)o1[3]};
      f32x4 obv;
      __builtin_memcpy(&obv, &ob, 16);
      nt_store_v4(obv, reinterpret_cast<float*>(hb_out + (size_t)r * NH_ + cg));
      if (t == T_ - 1) {   // exact f32 final h straight from the register master
        nt_store_v4(o0, out + (size_t)T_ * B_ * NO_ + (size_t)r * NH_ + cg);
        nt_store_v4(o1, out + (size_t)T_ * B_ * NO_ + (size_t)r * NH_ + cg + 4);
      }
    }
    __syncthreads();   // drain h stores
    if (tid == 0)
      __hip_atomic_fetch_add(flags + cb * 16, 1, __ATOMIC_RELEASE, __HIP_MEMORY_SCOPE_AGENT);
  }

  // ---- epilogue: y_{T-1} (state_512 lives at parity 0)
  if (tid < 32) spin_ge(flags + tid * 16, 8 * T_);
  __syncthreads();
  dec_tile(bid, tid, hb /*par0*/, Wdec, b_dec, out + (size_t)(T_ - 1) * B_ * NO_, Ds);
}

extern "C" void kernel_launch(void* const* d_in, const int* in_sizes, int n_in,
                              void* d_out, int out_size, void* d_ws, size_t ws_size,
                              hipStream_t stream) {
  const float* x     = (const float*)d_in[0];
  const float* dt_p  = (const float*)d_in[1];
  const float* a_p   = (const float*)d_in[2];
  const float* W_enc = (const float*)d_in[3];
  const float* b_enc = (const float*)d_in[4];
  const float* W_rec = (const float*)d_in[5];
  const float* b_rec = (const float*)d_in[6];
  const float* W_dec = (const float*)d_in[7];
  const float* b_dec = (const float*)d_in[8];
  float* out = (float*)d_out;

  char* p = (char*)d_ws;
  bf16_t* hb      = (bf16_t*)p;  p += 2 * (size_t)B_ * NH_ * 2;        // 2MB
  bf16_t* Wdec_b  = (bf16_t*)p;  p += (size_t)NO_ * NH_ * 2;           // 1MB
  float*  partial = (float*)p;   p += (size_t)NCB * NKB * 16384 * 4;   // 16MB
  int*    sync_   = (int*)p;     p += 4096;                            // ~19MB total

  hipMemsetAsync(hb, 0, (size_t)B_ * NH_ * 2, stream);   // parity-0 h = 0
  hipMemsetAsync(sync_, 0, 4096, stream);

  k_cvt<<<64, 256, 0, stream>>>(W_dec, Wdec_b, NO_ * NH_);

  k_prnn<<<dim3(256), dim3(256), 0, stream>>>(
      x, dt_p, a_p, W_rec, W_enc, Wdec_b, b_rec, b_enc, b_dec,
      hb, partial, sync_, out);
}